// Round 5
// baseline (451.820 us; speedup 1.0000x reference)
//
#include <hip/hip_runtime.h>
#include <hip/hip_bf16.h>
#include <math.h>

#define H_ 8
#define DK_ 32
#define B_ 4
#define M_ 64
#define N_ 512
#define D_ 256
#define F_ 1024

static constexpr float SCALE = 0.17677669529663687f; // 1/sqrt(32)
static constexpr float EPS = 1e-5f;

typedef __bf16 bf16x8 __attribute__((ext_vector_type(8)));
typedef float f32x4 __attribute__((ext_vector_type(4)));

__device__ inline float bfbits2f(unsigned int b) {
    union { unsigned int i; float f; } c; c.i = b << 16; return c.f;
}
__device__ inline void unpack8(uint4 u, float* f) {
    f[0] = bfbits2f(u.x & 0xffffu); f[1] = bfbits2f(u.x >> 16);
    f[2] = bfbits2f(u.y & 0xffffu); f[3] = bfbits2f(u.y >> 16);
    f[4] = bfbits2f(u.z & 0xffffu); f[5] = bfbits2f(u.z >> 16);
    f[6] = bfbits2f(u.w & 0xffffu); f[7] = bfbits2f(u.w >> 16);
}

// ---------------- mask dtype detection (uint8 vs int32 bools) ----------------
__global__ __launch_bounds__(256) void detect_kernel(const unsigned int* __restrict__ mask,
                                                     int* __restrict__ flags) {
    __shared__ int s2[256];
    int t = threadIdx.x;
    int cgt = 0;
    for (int i = 0; i < 128; ++i) {
        unsigned int w = mask[t * 128 + i];
        if (w > 1u) cgt++;
    }
    s2[t] = cgt;
    __syncthreads();
    if (t == 0) {
        int b = 0;
        for (int i = 0; i < 256; ++i) b += s2[i];
        flags[1] = (b > 0) ? 1 : 0;
    }
}

// ---------------- weight transpose+convert: dst[n*K+k] = bf16(src[k*N+n]) ----------------
struct TransArgs {
    const void* src[9];
    void* dst[9];
    int cum[9];
    int kl[9];   // log2 K
    int nl[9];   // log2 N
};

__global__ __launch_bounds__(256) void prep_transpose(TransArgs a, int total) {
    int i = blockIdx.x * 256 + threadIdx.x;
    if (i >= total) return;
    int t = 0;
    while (i >= a.cum[t]) t++;
    int j = i - (t == 0 ? 0 : a.cum[t - 1]);
    int K = 1 << a.kl[t];
    int n = j >> a.kl[t];
    int k = j & (K - 1);
    float v = ((const float*)a.src[t])[((size_t)k << a.nl[t]) + n];
    ((__hip_bfloat16*)a.dst[t])[j] = __float2bfloat16(v);
}

__global__ __launch_bounds__(256) void prep_bias(const float* bq, const float* bks,
                                                 const float* bvs, const float* bk,
                                                 const float* bv,
                                                 float* bqksvs, float* bkv) {
    int t = threadIdx.x;
    bqksvs[t] = bq[t];
    bqksvs[256 + t] = bks[t];
    bqksvs[512 + t] = bvs[t];
    bkv[t] = bk[t];
    bkv[256 + t] = bv[t];
}

// ---------------- block reduce (256 threads = 4 waves) ----------------
__device__ inline float block_reduce256(float v, bool is_max, float* sbuf) {
#pragma unroll
    for (int off = 32; off > 0; off >>= 1) {
        float o = __shfl_down(v, off, 64);
        v = is_max ? fmaxf(v, o) : (v + o);
    }
    int lane = threadIdx.x & 63, wid = threadIdx.x >> 6;
    if (lane == 0) sbuf[wid] = v;
    __syncthreads();
    float r;
    if (is_max) r = fmaxf(fmaxf(sbuf[0], sbuf[1]), fmaxf(sbuf[2], sbuf[3]));
    else        r = sbuf[0] + sbuf[1] + sbuf[2] + sbuf[3];
    __syncthreads();
    return r;
}

// ---------------- LayerNorm: fp32 in -> bf16 out ----------------
__global__ __launch_bounds__(256) void ln_kernel(const float* __restrict__ xin,
                                                 const float* __restrict__ g,
                                                 const float* __restrict__ bta,
                                                 __hip_bfloat16* __restrict__ out) {
    __shared__ float sbuf[4];
    int row = blockIdx.x, d = threadIdx.x;
    size_t idx = (size_t)row * 256 + d;
    float x = xin[idx];
    float s  = block_reduce256(x, false, sbuf);
    float ss = block_reduce256(x * x, false, sbuf);
    float mu = s * (1.f / 256.f);
    float var = ss * (1.f / 256.f) - mu * mu;
    float y = (x - mu) * rsqrtf(var + EPS) * g[d] + bta[d];
    out[idx] = __float2bfloat16(y);
}

// ---------------- generic MFMA GEMM: out(M,ldc) = A(M,K) @ BT(N,K)^T + bias ----------------
// flags: 1=relu, 4=resid f32, 8=out f32 (else bf16)
__global__ __launch_bounds__(256) void gemm64(const __hip_bfloat16* __restrict__ A,
                                              const __hip_bfloat16* __restrict__ BT,
                                              const float* __restrict__ bias,
                                              const float* __restrict__ resid,
                                              void* __restrict__ out,
                                              int K, int ldc, int flags) {
    __shared__ __align__(16) __bf16 As[64 * 32];
    __shared__ __align__(16) __bf16 Bs[64 * 32];
    const int rowBase = blockIdx.x * 64;
    const int colBase = blockIdx.y * 64;
    const int t = threadIdx.x;
    const int w = t >> 6;
    const int l = t & 63;
    const int lrow = l & 15;
    const int lk8 = (l >> 4) * 8;
    const int ar = t >> 2;
    const int ac = (t & 3) * 8;

    f32x4 acc[4] = {};
    for (int k0 = 0; k0 < K; k0 += 32) {
        bf16x8 av = *(const bf16x8*)(A + (size_t)(rowBase + ar) * K + k0 + ac);
        bf16x8 bv = *(const bf16x8*)(BT + (size_t)(colBase + ar) * K + k0 + ac);
        __syncthreads();
        *(bf16x8*)(As + ar * 32 + ac) = av;
        *(bf16x8*)(Bs + ar * 32 + ac) = bv;
        __syncthreads();
        bf16x8 af = *(const bf16x8*)(As + (w * 16 + lrow) * 32 + lk8);
#pragma unroll
        for (int c = 0; c < 4; ++c) {
            bf16x8 bf = *(const bf16x8*)(Bs + (c * 16 + lrow) * 32 + lk8);
            acc[c] = __builtin_amdgcn_mfma_f32_16x16x32_bf16(af, bf, acc[c], 0, 0, 0);
        }
    }
    int rbase = rowBase + w * 16 + ((l >> 4) * 4);
#pragma unroll
    for (int c = 0; c < 4; ++c) {
        int col = colBase + c * 16 + (l & 15);
        float bb = bias[col];
#pragma unroll
        for (int r = 0; r < 4; ++r) {
            int row = rbase + r;
            size_t oi = (size_t)row * ldc + col;
            float v = acc[c][r] + bb;
            if (flags & 1) v = fmaxf(v, 0.f);
            if (flags & 4) v += resid[oi];
            if (flags & 8) ((float*)out)[oi] = v;
            else ((__hip_bfloat16*)out)[oi] = __float2bfloat16(v);
        }
    }
}

// ---------------- edge GEMM v3: one block per (b,n); barrier-free K-loop.
// Fused: eperm(b,h,m,n,dk) store + masked scores sc(b,h,m,n). ----------------
__global__ __launch_bounds__(256) void edge_gemm3(const float* __restrict__ E,
                                                  const __hip_bfloat16* __restrict__ WeT,
                                                  const float* __restrict__ be,
                                                  const __hip_bfloat16* __restrict__ qkvs,
                                                  const __hip_bfloat16* __restrict__ kov,
                                                  const void* __restrict__ mask,
                                                  const int* __restrict__ flags,
                                                  __hip_bfloat16* __restrict__ eperm,
                                                  float* __restrict__ sc) {
    __shared__ __align__(16) __bf16 Cs[64 * 272];   // 34816 B, only used in epilogue
    const int bn = blockIdx.x;               // b*512 + n
    const int b = bn >> 9, n = bn & 511;
    const int t = threadIdx.x;
    const int w = t >> 6;
    const int l = t & 63;
    const int lrow = l & 15;
    const int lk8 = (l >> 4) * 8;
    const float* Ab = E + (size_t)bn * 64 * 256;

    f32x4 acc[4][4] = {};
    for (int k0 = 0; k0 < 256; k0 += 32) {
        // A fragments: direct global fp32 -> bf16 (each wave reads whole 64x32 tile)
        bf16x8 af[4];
#pragma unroll
        for (int rr = 0; rr < 4; ++rr) {
            const float* ap = Ab + (size_t)(rr * 16 + lrow) * 256 + k0 + lk8;
            float4 x0 = *(const float4*)ap;
            float4 x1 = *(const float4*)(ap + 4);
            af[rr][0] = (__bf16)x0.x; af[rr][1] = (__bf16)x0.y;
            af[rr][2] = (__bf16)x0.z; af[rr][3] = (__bf16)x0.w;
            af[rr][4] = (__bf16)x1.x; af[rr][5] = (__bf16)x1.y;
            af[rr][6] = (__bf16)x1.z; af[rr][7] = (__bf16)x1.w;
        }
#pragma unroll
        for (int c = 0; c < 4; ++c) {
            // B fragment: direct global read from WeT (row n_out, 8 contiguous k)
            bf16x8 bf = *(const bf16x8*)(WeT + (size_t)(w * 64 + c * 16 + lrow) * 256 + k0 + lk8);
#pragma unroll
            for (int rr = 0; rr < 4; ++rr)
                acc[rr][c] = __builtin_amdgcn_mfma_f32_16x16x32_bf16(af[rr], bf, acc[rr][c], 0, 0, 0);
        }
    }
    // epilogue: stage C (64 m x 256 d) with bias in LDS
#pragma unroll
    for (int c = 0; c < 4; ++c) {
        int col = w * 64 + c * 16 + (l & 15);
        float bb = be[col];
#pragma unroll
        for (int rr = 0; rr < 4; ++rr) {
#pragma unroll
            for (int r = 0; r < 4; ++r) {
                int m = rr * 16 + (l >> 4) * 4 + r;
                Cs[m * 272 + col] = (__bf16)(acc[rr][c][r] + bb);
            }
        }
    }
    __syncthreads();
    const bool u8 = flags[1] != 0;
    const int seg = t & 31;
    const int h = seg >> 2;
    const int dk8 = (seg & 3) * 8;
#pragma unroll
    for (int j = 0; j < 8; ++j) {
        int m = j * 8 + (t >> 5);
        uint4 ev4 = *(const uint4*)(Cs + m * 272 + seg * 8);
        // eperm store (coalesced 64B runs)
        size_t bhm = (size_t)((b * 8 + h) * 64 + m);
        *(uint4*)(eperm + (bhm * 512 + n) * 32 + dk8) = ev4;
        // fused score partial: sum_dk (q+e)(k+e) over this thread's 8 dk
        float ev[8], qf[8], kf[8];
        unpack8(ev4, ev);
        uint4 qv4 = *(const uint4*)(qkvs + (size_t)(b * 64 + m) * 768 + h * 32 + dk8);
        uint4 kv4 = *(const uint4*)(kov + (size_t)(b * 512 + n) * 512 + h * 32 + dk8);
        unpack8(qv4, qf);
        unpack8(kv4, kf);
        float p = 0.f;
#pragma unroll
        for (int i = 0; i < 8; ++i)
            p += (qf[i] + ev[i]) * (kf[i] + ev[i]);
        p += __shfl_xor(p, 1, 64);
        p += __shfl_xor(p, 2, 64);
        if ((t & 3) == 0) {
            int mi = (b * 512 + n) * 64 + m;
            int mk = u8 ? (int)((const unsigned char*)mask)[mi] : ((const int*)mask)[mi];
            sc[bhm * 512 + n] = mk ? p * SCALE : -__builtin_inff();
        }
    }
}

// ---------------- fused softmax + attn output: one block per (b,h,m) ----------------
__global__ __launch_bounds__(256) void smax_attnout(const float* __restrict__ sc,
                                                    const __hip_bfloat16* __restrict__ qkvs,
                                                    const __hip_bfloat16* __restrict__ kov,
                                                    const __hip_bfloat16* __restrict__ eperm,
                                                    __hip_bfloat16* __restrict__ AO) {
    __shared__ float sbuf[4];
    __shared__ float attnS[512];
    __shared__ float selfSc;
    __shared__ float selfA;
    __shared__ float red[16][8];
    int bhm = blockIdx.x;
    int m = bhm & 63;
    int h = (bhm >> 6) & 7;
    int b = bhm >> 9;
    int t = threadIdx.x;
    if (t == 0) {
        const __hip_bfloat16* q  = qkvs + (size_t)(b * 64 + m) * 768 + h * 32;
        const __hip_bfloat16* ks = q + 256;
        float s = 0.f;
        for (int i = 0; i < 32; ++i) s += __bfloat162float(q[i]) * __bfloat162float(ks[i]);
        selfSc = s * SCALE;
    }
    __syncthreads();
    float sv = selfSc;
    float s0 = sc[(size_t)bhm * 512 + t];
    float s1 = sc[(size_t)bhm * 512 + 256 + t];
    float mx = block_reduce256(fmaxf(fmaxf(s0, s1), sv), true, sbuf);
    float e0 = __expf(s0 - mx);
    float e1 = __expf(s1 - mx);
    float eself = __expf(sv - mx);
    float sum = block_reduce256(e0 + e1 + (t == 0 ? eself : 0.f), false, sbuf);
    float inv = 1.f / sum;
    attnS[t] = e0 * inv;
    attnS[256 + t] = e1 * inv;
    if (t == 0) selfA = eself * inv;
    __syncthreads();

    // attn @ (V+E): thread (d8=(t&3)*8, ng=t>>2), 8 n-iters
    const int d8 = (t & 3) * 8;
    const int ng = t >> 2;
    const int w = t >> 6, l = t & 63;
    const __hip_bfloat16* ebase = eperm + (size_t)bhm * 512 * 32;
    const __hip_bfloat16* vbase = kov + (size_t)(b * 512) * 512 + 256 + h * 32;
    float accv[8] = {};
#pragma unroll
    for (int i = 0; i < 8; ++i) {
        int n = ng + i * 64;
        float a = attnS[n];
        float ev[8], vv[8];
        uint4 e4 = *(const uint4*)(ebase + (size_t)n * 32 + d8);
        uint4 v4 = *(const uint4*)(vbase + (size_t)n * 512 + d8);
        unpack8(e4, ev);
        unpack8(v4, vv);
#pragma unroll
        for (int k = 0; k < 8; ++k) accv[k] += a * (vv[k] + ev[k]);
    }
    // reduce over ng within wave (lanes sharing l&3)
#pragma unroll
    for (int off = 4; off <= 32; off <<= 1) {
#pragma unroll
        for (int k = 0; k < 8; ++k) accv[k] += __shfl_xor(accv[k], off, 64);
    }
    if ((l >> 2) == 0) {
#pragma unroll
        for (int k = 0; k < 8; ++k) red[w * 4 + (l & 3)][k] = accv[k];
    }
    __syncthreads();
    if (t < 32) {
        int slot = t >> 3, elem = t & 7;
        float r = red[slot][elem] + red[4 + slot][elem] + red[8 + slot][elem] + red[12 + slot][elem];
        float vs = __bfloat162float(qkvs[(size_t)(b * 64 + m) * 768 + 512 + h * 32 + t]);
        r += selfA * vs;
        AO[(size_t)(b * 64 + m) * 256 + h * 32 + t] = __float2bfloat16(r);
    }
}

extern "C" void kernel_launch(void* const* d_in, const int* in_sizes, int n_in,
                              void* d_out, int out_size, void* d_ws, size_t ws_size,
                              hipStream_t stream) {
    const float* machine_emb = (const float*)d_in[0];
    const float* op_emb      = (const float*)d_in[1];
    const float* edge_emb    = (const float*)d_in[2];
    const void*  o2m_mask    = d_in[3];

    char* p = (char*)d_ws;
    int* flags = (int*)p;                        p += 256;
    __hip_bfloat16* WqksvsT = (__hip_bfloat16*)p; p += 196608 * 2;
    __hip_bfloat16* WkvT    = (__hip_bfloat16*)p; p += 131072 * 2;
    __hip_bfloat16* WoT     = (__hip_bfloat16*)p; p += 65536 * 2;
    __hip_bfloat16* WeT     = (__hip_bfloat16*)p; p += 65536 * 2;
    __hip_bfloat16* Wf1T    = (__hip_bfloat16*)p; p += 262144 * 2;
    __hip_bfloat16* Wf2T    = (__hip_bfloat16*)p; p += 262144 * 2;
    float* bqksvs           = (float*)p;          p += 768 * 4;
    float* bkv              = (float*)p;          p += 512 * 4;
    __hip_bfloat16* mnorm   = (__hip_bfloat16*)p; p += 65536 * 2;
    __hip_bfloat16* onorm   = (__hip_bfloat16*)p; p += 524288 * 2;
    __hip_bfloat16* qkvs    = (__hip_bfloat16*)p; p += 196608 * 2;
    __hip_bfloat16* kov     = (__hip_bfloat16*)p; p += 1048576 * 2;
    __hip_bfloat16* eperm   = (__hip_bfloat16*)p; p += (size_t)33554432 * 2;
    float* sc        = (float*)p;                p += (size_t)1048576 * 4;
    __hip_bfloat16* AO = (__hip_bfloat16*)p;     p += 65536 * 2;
    float* m2        = (float*)p;                p += 65536 * 4;
    __hip_bfloat16* hn = (__hip_bfloat16*)p;     p += 65536 * 2;
    __hip_bfloat16* h1 = (__hip_bfloat16*)p;     p += 262144 * 2;

    // prep: transpose+convert all weights to (N,K) bf16
    TransArgs ta;
    const int srcIdx[9] = {4, 12, 14, 6, 8, 10, 16, 24, 26};
    void* dsts[9] = {WqksvsT, WqksvsT + 65536, WqksvsT + 131072,
                     WkvT, WkvT + 65536, WoT, WeT, Wf1T, Wf2T};
    const int sizes9[9] = {65536, 65536, 65536, 65536, 65536, 65536, 65536, 262144, 262144};
    const int kl9[9] = {8, 8, 8, 8, 8, 8, 8, 8, 10};
    const int nl9[9] = {8, 8, 8, 8, 8, 8, 8, 10, 8};
    int cum = 0;
    for (int i = 0; i < 9; ++i) {
        ta.src[i] = d_in[srcIdx[i]];
        ta.dst[i] = dsts[i];
        cum += sizes9[i];
        ta.cum[i] = cum;
        ta.kl[i] = kl9[i];
        ta.nl[i] = nl9[i];
    }

    hipLaunchKernelGGL(detect_kernel, dim3(1), dim3(256), 0, stream,
                       (const unsigned int*)o2m_mask, flags);
    hipLaunchKernelGGL(prep_transpose, dim3((cum + 255) / 256), dim3(256), 0, stream, ta, cum);
    hipLaunchKernelGGL(prep_bias, dim3(1), dim3(256), 0, stream,
                       (const float*)d_in[5], (const float*)d_in[13],
                       (const float*)d_in[15], (const float*)d_in[7],
                       (const float*)d_in[9], bqksvs, bkv);

    // LayerNorms (fp32 in -> bf16 out)
    hipLaunchKernelGGL(ln_kernel, dim3(256), dim3(256), 0, stream,
                       machine_emb, (const float*)d_in[18], (const float*)d_in[19], mnorm);
    hipLaunchKernelGGL(ln_kernel, dim3(2048), dim3(256), 0, stream,
                       op_emb, (const float*)d_in[22], (const float*)d_in[23], onorm);

    // projections (MFMA) — needed by edge_gemm3's fused scores
    hipLaunchKernelGGL(gemm64, dim3(4, 12), dim3(256), 0, stream,
                       mnorm, WqksvsT, bqksvs, nullptr, qkvs, 256, 768, 0);
    hipLaunchKernelGGL(gemm64, dim3(32, 8), dim3(256), 0, stream,
                       onorm, WkvT, bkv, nullptr, kov, 256, 512, 0);

    // edge GEMM + fused eperm store + fused masked scores
    hipLaunchKernelGGL(edge_gemm3, dim3(2048), dim3(256), 0, stream,
                       edge_emb, WeT, (const float*)d_in[17],
                       qkvs, kov, o2m_mask, flags, eperm, sc);

    // fused softmax + attn output
    hipLaunchKernelGGL(smax_attnout, dim3(2048), dim3(256), 0, stream,
                       sc, qkvs, kov, eperm, AO);

    // out proj + residual -> m2 (f32), LN2, FFN
    hipLaunchKernelGGL(gemm64, dim3(4, 4), dim3(256), 0, stream,
                       AO, WoT, (const float*)d_in[11], machine_emb, m2, 256, 256, 4 | 8);
    hipLaunchKernelGGL(ln_kernel, dim3(256), dim3(256), 0, stream,
                       m2, (const float*)d_in[20], (const float*)d_in[21], hn);
    hipLaunchKernelGGL(gemm64, dim3(4, 16), dim3(256), 0, stream,
                       hn, Wf1T, (const float*)d_in[25], nullptr, h1, 256, 1024, 1);
    hipLaunchKernelGGL(gemm64, dim3(4, 4), dim3(256), 0, stream,
                       h1, Wf2T, (const float*)d_in[27], m2, (float*)d_out, 1024, 256, 4 | 8);
}

// Round 6
// 382.166 us; speedup vs baseline: 1.1823x; 1.1823x over previous
//
#include <hip/hip_runtime.h>
#include <hip/hip_bf16.h>
#include <math.h>

#define H_ 8
#define DK_ 32
#define B_ 4
#define M_ 64
#define N_ 512
#define D_ 256
#define F_ 1024

static constexpr float SCALE = 0.17677669529663687f; // 1/sqrt(32)
static constexpr float EPS = 1e-5f;

typedef __bf16 bf16x8 __attribute__((ext_vector_type(8)));
typedef float f32x4 __attribute__((ext_vector_type(4)));

__device__ inline float bfbits2f(unsigned int b) {
    union { unsigned int i; float f; } c; c.i = b << 16; return c.f;
}
__device__ inline void unpack8(uint4 u, float* f) {
    f[0] = bfbits2f(u.x & 0xffffu); f[1] = bfbits2f(u.x >> 16);
    f[2] = bfbits2f(u.y & 0xffffu); f[3] = bfbits2f(u.y >> 16);
    f[4] = bfbits2f(u.z & 0xffffu); f[5] = bfbits2f(u.z >> 16);
    f[6] = bfbits2f(u.w & 0xffffu); f[7] = bfbits2f(u.w >> 16);
}

// ---------------- mask dtype detection (uint8 vs int32 bools) ----------------
__global__ __launch_bounds__(256) void detect_kernel(const unsigned int* __restrict__ mask,
                                                     int* __restrict__ flags) {
    __shared__ int s2[256];
    int t = threadIdx.x;
    int cgt = 0;
    for (int i = 0; i < 128; ++i) {
        unsigned int w = mask[t * 128 + i];
        if (w > 1u) cgt++;
    }
    s2[t] = cgt;
    __syncthreads();
    if (t == 0) {
        int b = 0;
        for (int i = 0; i < 256; ++i) b += s2[i];
        flags[1] = (b > 0) ? 1 : 0;
    }
}

// ---------------- tiled weight transpose+convert: dst[n*K+k] = bf16(src[k*N+n]) ----------------
struct TTArgs {
    const void* src[9];
    void* dst[9];
    int tcum[9];   // cumulative 64x64 tile counts
    int kl[9];     // log2 K
    int nl[9];     // log2 N
};

__global__ __launch_bounds__(256) void prep_transpose(TTArgs a) {
    __shared__ float ld[64][65];
    int bx = blockIdx.x;
    int ti = 0;
    while (bx >= a.tcum[ti]) ti++;
    int j = bx - (ti ? a.tcum[ti - 1] : 0);
    int K = 1 << a.kl[ti], N = 1 << a.nl[ti];
    int ntn = N >> 6;
    int kt = j / ntn, nt = j - kt * ntn;
    const float* src = (const float*)a.src[ti];
    __hip_bfloat16* dst = (__hip_bfloat16*)a.dst[ti];
    int t = threadIdx.x;
    int col = t & 63, r0 = t >> 6;
#pragma unroll
    for (int i = 0; i < 16; ++i) {
        int r = i * 4 + r0;
        ld[r][col] = src[(size_t)(kt * 64 + r) * N + nt * 64 + col];
    }
    __syncthreads();
#pragma unroll
    for (int i = 0; i < 16; ++i) {
        int r = i * 4 + r0;
        dst[(size_t)(nt * 64 + r) * K + kt * 64 + col] = __float2bfloat16(ld[col][r]);
    }
}

__global__ __launch_bounds__(256) void prep_bias(const float* bq, const float* bks,
                                                 const float* bvs, const float* bk,
                                                 const float* bv,
                                                 float* bqksvs, float* bkv) {
    int t = threadIdx.x;
    bqksvs[t] = bq[t];
    bqksvs[256 + t] = bks[t];
    bqksvs[512 + t] = bvs[t];
    bkv[t] = bk[t];
    bkv[256 + t] = bv[t];
}

// ---------------- block reduce (256 threads = 4 waves) ----------------
__device__ inline float block_reduce256(float v, bool is_max, float* sbuf) {
#pragma unroll
    for (int off = 32; off > 0; off >>= 1) {
        float o = __shfl_down(v, off, 64);
        v = is_max ? fmaxf(v, o) : (v + o);
    }
    int lane = threadIdx.x & 63, wid = threadIdx.x >> 6;
    if (lane == 0) sbuf[wid] = v;
    __syncthreads();
    float r;
    if (is_max) r = fmaxf(fmaxf(sbuf[0], sbuf[1]), fmaxf(sbuf[2], sbuf[3]));
    else        r = sbuf[0] + sbuf[1] + sbuf[2] + sbuf[3];
    __syncthreads();
    return r;
}

// ---------------- LayerNorm: fp32 in -> bf16 out ----------------
__global__ __launch_bounds__(256) void ln_kernel(const float* __restrict__ xin,
                                                 const float* __restrict__ g,
                                                 const float* __restrict__ bta,
                                                 __hip_bfloat16* __restrict__ out) {
    __shared__ float sbuf[4];
    int row = blockIdx.x, d = threadIdx.x;
    size_t idx = (size_t)row * 256 + d;
    float x = xin[idx];
    float s  = block_reduce256(x, false, sbuf);
    float ss = block_reduce256(x * x, false, sbuf);
    float mu = s * (1.f / 256.f);
    float var = ss * (1.f / 256.f) - mu * mu;
    float y = (x - mu) * rsqrtf(var + EPS) * g[d] + bta[d];
    out[idx] = __float2bfloat16(y);
}

// ---------------- generic MFMA GEMM: out(M,ldc) = A(M,K) @ BT(N,K)^T + bias ----------------
// flags: 1=relu, 4=resid f32, 8=out f32 (else bf16)
__global__ __launch_bounds__(256) void gemm64(const __hip_bfloat16* __restrict__ A,
                                              const __hip_bfloat16* __restrict__ BT,
                                              const float* __restrict__ bias,
                                              const float* __restrict__ resid,
                                              void* __restrict__ out,
                                              int K, int ldc, int flags) {
    __shared__ __align__(16) __bf16 As[64 * 40];
    __shared__ __align__(16) __bf16 Bs[64 * 40];
    const int rowBase = blockIdx.x * 64;
    const int colBase = blockIdx.y * 64;
    const int t = threadIdx.x;
    const int w = t >> 6;
    const int l = t & 63;
    const int lrow = l & 15;
    const int lk8 = (l >> 4) * 8;
    const int ar = t >> 2;
    const int ac = (t & 3) * 8;

    f32x4 acc[4] = {};
    for (int k0 = 0; k0 < K; k0 += 32) {
        bf16x8 av = *(const bf16x8*)(A + (size_t)(rowBase + ar) * K + k0 + ac);
        bf16x8 bv = *(const bf16x8*)(BT + (size_t)(colBase + ar) * K + k0 + ac);
        __syncthreads();
        *(bf16x8*)(As + ar * 40 + ac) = av;
        *(bf16x8*)(Bs + ar * 40 + ac) = bv;
        __syncthreads();
        bf16x8 af = *(const bf16x8*)(As + (w * 16 + lrow) * 40 + lk8);
#pragma unroll
        for (int c = 0; c < 4; ++c) {
            bf16x8 bf = *(const bf16x8*)(Bs + (c * 16 + lrow) * 40 + lk8);
            acc[c] = __builtin_amdgcn_mfma_f32_16x16x32_bf16(af, bf, acc[c], 0, 0, 0);
        }
    }
    int rbase = rowBase + w * 16 + ((l >> 4) * 4);
#pragma unroll
    for (int c = 0; c < 4; ++c) {
        int col = colBase + c * 16 + (l & 15);
        float bb = bias[col];
#pragma unroll
        for (int r = 0; r < 4; ++r) {
            int row = rbase + r;
            size_t oi = (size_t)row * ldc + col;
            float v = acc[c][r] + bb;
            if (flags & 1) v = fmaxf(v, 0.f);
            if (flags & 4) v += resid[oi];
            if (flags & 8) ((float*)out)[oi] = v;
            else ((__hip_bfloat16*)out)[oi] = __float2bfloat16(v);
        }
    }
}

// ---------------- edge GEMM v4: one block per (b,n). A staged in padded LDS,
// B direct from L1-resident WeT. Fused eperm store + masked scores in (b,n,h,m). --------
__global__ __launch_bounds__(256) void edge_gemm4(const float* __restrict__ E,
                                                  const __hip_bfloat16* __restrict__ WeT,
                                                  const float* __restrict__ be,
                                                  const __hip_bfloat16* __restrict__ qkvs,
                                                  const __hip_bfloat16* __restrict__ kov,
                                                  const void* __restrict__ mask,
                                                  const int* __restrict__ flags,
                                                  __hip_bfloat16* __restrict__ eperm,
                                                  float* __restrict__ scBn) {
    __shared__ __align__(16) __bf16 smem[64 * 272];   // 34816 B
    __bf16* As = smem;                                // 64 x 40 (K-loop)
    __bf16* Cs = smem;                                // 64 x 272 (epilogue)
    const int bn = blockIdx.x;               // b*512 + n
    const int b = bn >> 9, n = bn & 511;
    const int t = threadIdx.x;
    const int w = t >> 6;
    const int l = t & 63;
    const int lrow = l & 15;
    const int lk8 = (l >> 4) * 8;
    const int ar = t >> 2;
    const int ac = (t & 3) * 8;
    const float* Ab = E + (size_t)bn * 64 * 256;

    f32x4 acc[4][4] = {};
    for (int k0 = 0; k0 < 256; k0 += 32) {
        const float* ap = Ab + (size_t)ar * 256 + k0 + ac;
        float4 x0 = *(const float4*)ap;
        float4 x1 = *(const float4*)(ap + 4);
        bf16x8 av;
        av[0] = (__bf16)x0.x; av[1] = (__bf16)x0.y; av[2] = (__bf16)x0.z; av[3] = (__bf16)x0.w;
        av[4] = (__bf16)x1.x; av[5] = (__bf16)x1.y; av[6] = (__bf16)x1.z; av[7] = (__bf16)x1.w;
        __syncthreads();
        *(bf16x8*)(As + ar * 40 + ac) = av;
        __syncthreads();
        bf16x8 af[4];
#pragma unroll
        for (int rr = 0; rr < 4; ++rr)
            af[rr] = *(const bf16x8*)(As + (rr * 16 + lrow) * 40 + lk8);
#pragma unroll
        for (int c = 0; c < 4; ++c) {
            bf16x8 bf = *(const bf16x8*)(WeT + (size_t)(w * 64 + c * 16 + lrow) * 256 + k0 + lk8);
#pragma unroll
            for (int rr = 0; rr < 4; ++rr)
                acc[rr][c] = __builtin_amdgcn_mfma_f32_16x16x32_bf16(af[rr], bf, acc[rr][c], 0, 0, 0);
        }
    }
    __syncthreads();
    // epilogue: stage C (64 m x 256 d) with bias in LDS
#pragma unroll
    for (int c = 0; c < 4; ++c) {
        int col = w * 64 + c * 16 + (l & 15);
        float bb = be[col];
#pragma unroll
        for (int rr = 0; rr < 4; ++rr) {
#pragma unroll
            for (int r = 0; r < 4; ++r) {
                int m = rr * 16 + (l >> 4) * 4 + r;
                Cs[m * 272 + col] = (__bf16)(acc[rr][c][r] + bb);
            }
        }
    }
    __syncthreads();
    const bool u8 = flags[1] != 0;
    const int seg = t & 31;
    const int h = seg >> 2;
    const int dk8 = (seg & 3) * 8;
#pragma unroll
    for (int j = 0; j < 8; ++j) {
        int m = j * 8 + (t >> 5);
        uint4 ev4 = *(const uint4*)(Cs + m * 272 + seg * 8);
        // eperm store (coalesced 64B runs)
        size_t bhm = (size_t)((b * 8 + h) * 64 + m);
        *(uint4*)(eperm + (bhm * 512 + n) * 32 + dk8) = ev4;
        // fused score partial: sum_dk (q+e)(k+e) over this thread's 8 dk
        float ev[8], qf[8], kf[8];
        unpack8(ev4, ev);
        uint4 qv4 = *(const uint4*)(qkvs + (size_t)(b * 64 + m) * 768 + h * 32 + dk8);
        uint4 kv4 = *(const uint4*)(kov + (size_t)(b * 512 + n) * 512 + h * 32 + dk8);
        unpack8(qv4, qf);
        unpack8(kv4, kf);
        float p = 0.f;
#pragma unroll
        for (int i = 0; i < 8; ++i)
            p += (qf[i] + ev[i]) * (kf[i] + ev[i]);
        p += __shfl_xor(p, 1, 64);
        p += __shfl_xor(p, 2, 64);
        if ((t & 3) == 0) {
            int mi = (b * 512 + n) * 64 + m;
            int mk = u8 ? (int)((const unsigned char*)mask)[mi] : ((const int*)mask)[mi];
            // contiguous per-block 2KB run: layout (b, n, h*64+m)
            scBn[(size_t)bn * 512 + h * 64 + m] = mk ? p * SCALE : -__builtin_inff();
        }
    }
}

// ---------------- transpose scores (b,n,hm) -> (b,hm,n) ----------------
__global__ __launch_bounds__(256) void transpose_sc(const float* __restrict__ in,
                                                    float* __restrict__ out) {
    __shared__ float ld[64][65];
    int b = blockIdx.z;
    int n0 = blockIdx.x * 64;
    int hm0 = blockIdx.y * 64;
    int t = threadIdx.x;
    int col = t & 63, r0 = t >> 6;
#pragma unroll
    for (int i = 0; i < 16; ++i) {
        int r = i * 4 + r0;
        ld[r][col] = in[((size_t)(b * 512 + n0 + r)) * 512 + hm0 + col];
    }
    __syncthreads();
#pragma unroll
    for (int i = 0; i < 16; ++i) {
        int r = i * 4 + r0;
        out[((size_t)(b * 512 + hm0 + r)) * 512 + n0 + col] = ld[col][r];
    }
}

// ---------------- fused softmax + attn output: one block per (b,h,m) ----------------
__global__ __launch_bounds__(256) void smax_attnout(const float* __restrict__ sc,
                                                    const __hip_bfloat16* __restrict__ qkvs,
                                                    const __hip_bfloat16* __restrict__ kov,
                                                    const __hip_bfloat16* __restrict__ eperm,
                                                    __hip_bfloat16* __restrict__ AO) {
    __shared__ float sbuf[4];
    __shared__ float attnS[512];
    __shared__ float selfSc;
    __shared__ float selfA;
    __shared__ float red[16][8];
    int bhm = blockIdx.x;
    int m = bhm & 63;
    int h = (bhm >> 6) & 7;
    int b = bhm >> 9;
    int t = threadIdx.x;
    if (t == 0) {
        const __hip_bfloat16* q  = qkvs + (size_t)(b * 64 + m) * 768 + h * 32;
        const __hip_bfloat16* ks = q + 256;
        float s = 0.f;
        for (int i = 0; i < 32; ++i) s += __bfloat162float(q[i]) * __bfloat162float(ks[i]);
        selfSc = s * SCALE;
    }
    __syncthreads();
    float sv = selfSc;
    float s0 = sc[(size_t)bhm * 512 + t];
    float s1 = sc[(size_t)bhm * 512 + 256 + t];
    float mx = block_reduce256(fmaxf(fmaxf(s0, s1), sv), true, sbuf);
    float e0 = __expf(s0 - mx);
    float e1 = __expf(s1 - mx);
    float eself = __expf(sv - mx);
    float sum = block_reduce256(e0 + e1 + (t == 0 ? eself : 0.f), false, sbuf);
    float inv = 1.f / sum;
    attnS[t] = e0 * inv;
    attnS[256 + t] = e1 * inv;
    if (t == 0) selfA = eself * inv;
    __syncthreads();

    // attn @ (V+E): thread (d8=(t&3)*8, ng=t>>2), 8 n-iters
    const int d8 = (t & 3) * 8;
    const int ng = t >> 2;
    const int w = t >> 6, l = t & 63;
    const __hip_bfloat16* ebase = eperm + (size_t)bhm * 512 * 32;
    const __hip_bfloat16* vbase = kov + (size_t)(b * 512) * 512 + 256 + h * 32;
    float accv[8] = {};
#pragma unroll
    for (int i = 0; i < 8; ++i) {
        int n = ng + i * 64;
        float a = attnS[n];
        float ev[8], vv[8];
        uint4 e4 = *(const uint4*)(ebase + (size_t)n * 32 + d8);
        uint4 v4 = *(const uint4*)(vbase + (size_t)n * 512 + d8);
        unpack8(e4, ev);
        unpack8(v4, vv);
#pragma unroll
        for (int k = 0; k < 8; ++k) accv[k] += a * (vv[k] + ev[k]);
    }
#pragma unroll
    for (int off = 4; off <= 32; off <<= 1) {
#pragma unroll
        for (int k = 0; k < 8; ++k) accv[k] += __shfl_xor(accv[k], off, 64);
    }
    if ((l >> 2) == 0) {
#pragma unroll
        for (int k = 0; k < 8; ++k) red[w * 4 + (l & 3)][k] = accv[k];
    }
    __syncthreads();
    if (t < 32) {
        int slot = t >> 3, elem = t & 7;
        float r = red[slot][elem] + red[4 + slot][elem] + red[8 + slot][elem] + red[12 + slot][elem];
        float vs = __bfloat162float(qkvs[(size_t)(b * 64 + m) * 768 + 512 + h * 32 + t]);
        r += selfA * vs;
        AO[(size_t)(b * 64 + m) * 256 + h * 32 + t] = __float2bfloat16(r);
    }
}

extern "C" void kernel_launch(void* const* d_in, const int* in_sizes, int n_in,
                              void* d_out, int out_size, void* d_ws, size_t ws_size,
                              hipStream_t stream) {
    const float* machine_emb = (const float*)d_in[0];
    const float* op_emb      = (const float*)d_in[1];
    const float* edge_emb    = (const float*)d_in[2];
    const void*  o2m_mask    = d_in[3];

    char* p = (char*)d_ws;
    int* flags = (int*)p;                        p += 256;
    __hip_bfloat16* WqksvsT = (__hip_bfloat16*)p; p += 196608 * 2;
    __hip_bfloat16* WkvT    = (__hip_bfloat16*)p; p += 131072 * 2;
    __hip_bfloat16* WoT     = (__hip_bfloat16*)p; p += 65536 * 2;
    __hip_bfloat16* WeT     = (__hip_bfloat16*)p; p += 65536 * 2;
    __hip_bfloat16* Wf1T    = (__hip_bfloat16*)p; p += 262144 * 2;
    __hip_bfloat16* Wf2T    = (__hip_bfloat16*)p; p += 262144 * 2;
    float* bqksvs           = (float*)p;          p += 768 * 4;
    float* bkv              = (float*)p;          p += 512 * 4;
    __hip_bfloat16* mnorm   = (__hip_bfloat16*)p; p += 65536 * 2;
    __hip_bfloat16* onorm   = (__hip_bfloat16*)p; p += 524288 * 2;
    __hip_bfloat16* qkvs    = (__hip_bfloat16*)p; p += 196608 * 2;
    __hip_bfloat16* kov     = (__hip_bfloat16*)p; p += 1048576 * 2;
    __hip_bfloat16* eperm   = (__hip_bfloat16*)p; p += (size_t)33554432 * 2;
    float* scBn      = (float*)p;                p += (size_t)1048576 * 4;
    float* scT       = (float*)p;                p += (size_t)1048576 * 4;
    __hip_bfloat16* AO = (__hip_bfloat16*)p;     p += 65536 * 2;
    float* m2        = (float*)p;                p += 65536 * 4;
    __hip_bfloat16* hn = (__hip_bfloat16*)p;     p += 65536 * 2;
    __hip_bfloat16* h1 = (__hip_bfloat16*)p;     p += 262144 * 2;

    // prep: tiled transpose+convert all weights to (N,K) bf16
    TTArgs ta;
    const int srcIdx[9] = {4, 12, 14, 6, 8, 10, 16, 24, 26};
    void* dsts[9] = {WqksvsT, WqksvsT + 65536, WqksvsT + 131072,
                     WkvT, WkvT + 65536, WoT, WeT, Wf1T, Wf2T};
    const int kl9[9] = {8, 8, 8, 8, 8, 8, 8, 8, 10};
    const int nl9[9] = {8, 8, 8, 8, 8, 8, 8, 10, 8};
    int tcum = 0;
    for (int i = 0; i < 9; ++i) {
        ta.src[i] = d_in[srcIdx[i]];
        ta.dst[i] = dsts[i];
        int tiles = (1 << (kl9[i] - 6)) * (1 << (nl9[i] - 6));
        tcum += tiles;
        ta.tcum[i] = tcum;
        ta.kl[i] = kl9[i];
        ta.nl[i] = nl9[i];
    }

    hipLaunchKernelGGL(detect_kernel, dim3(1), dim3(256), 0, stream,
                       (const unsigned int*)o2m_mask, flags);
    hipLaunchKernelGGL(prep_transpose, dim3(tcum), dim3(256), 0, stream, ta);
    hipLaunchKernelGGL(prep_bias, dim3(1), dim3(256), 0, stream,
                       (const float*)d_in[5], (const float*)d_in[13],
                       (const float*)d_in[15], (const float*)d_in[7],
                       (const float*)d_in[9], bqksvs, bkv);

    // LayerNorms (fp32 in -> bf16 out)
    hipLaunchKernelGGL(ln_kernel, dim3(256), dim3(256), 0, stream,
                       machine_emb, (const float*)d_in[18], (const float*)d_in[19], mnorm);
    hipLaunchKernelGGL(ln_kernel, dim3(2048), dim3(256), 0, stream,
                       op_emb, (const float*)d_in[22], (const float*)d_in[23], onorm);

    // projections (MFMA)
    hipLaunchKernelGGL(gemm64, dim3(4, 12), dim3(256), 0, stream,
                       mnorm, WqksvsT, bqksvs, nullptr, qkvs, 256, 768, 0);
    hipLaunchKernelGGL(gemm64, dim3(32, 8), dim3(256), 0, stream,
                       onorm, WkvT, bkv, nullptr, kov, 256, 512, 0);

    // edge GEMM + fused eperm store + fused masked scores (contiguous layout)
    hipLaunchKernelGGL(edge_gemm4, dim3(2048), dim3(256), 0, stream,
                       edge_emb, WeT, (const float*)d_in[17],
                       qkvs, kov, o2m_mask, flags, eperm, scBn);

    // transpose scores to (b,h,m,n)
    hipLaunchKernelGGL(transpose_sc, dim3(8, 8, 4), dim3(256), 0, stream, scBn, scT);

    // fused softmax + attn output
    hipLaunchKernelGGL(smax_attnout, dim3(2048), dim3(256), 0, stream,
                       scT, qkvs, kov, eperm, AO);

    // out proj + residual -> m2 (f32), LN2, FFN
    hipLaunchKernelGGL(gemm64, dim3(4, 4), dim3(256), 0, stream,
                       AO, WoT, (const float*)d_in[11], machine_emb, m2, 256, 256, 4 | 8);
    hipLaunchKernelGGL(ln_kernel, dim3(256), dim3(256), 0, stream,
                       m2, (const float*)d_in[20], (const float*)d_in[21], hn);
    hipLaunchKernelGGL(gemm64, dim3(4, 16), dim3(256), 0, stream,
                       hn, Wf1T, (const float*)d_in[25], nullptr, h1, 256, 1024, 1);
    hipLaunchKernelGGL(gemm64, dim3(4, 4), dim3(256), 0, stream,
                       h1, Wf2T, (const float*)d_in[27], m2, (float*)d_out, 1024, 256, 4 | 8);
}